// Round 1
// baseline (420.020 us; speedup 1.0000x reference)
//
#include <hip/hip_runtime.h>
#include <hip/hip_bf16.h>
#include <math.h>

using bf16 = __hip_bfloat16;
typedef __attribute__((ext_vector_type(8))) short short8;
typedef __attribute__((ext_vector_type(4))) float f32x4;
typedef __attribute__((ext_vector_type(4))) unsigned int uint4v;

#define BATCH 8192
#define SDIM  70
#define NS    64
#define NW    6
#define HID   1024
#define NA    4096
#define KPAD  96   // states K padded 70 -> 96 (multiple of 32)

// ---------------- conversion kernels ----------------

// states fp32 [BATCH][70] -> bf16 [BATCH][96], zero-padded k in [70,96)
__global__ __launch_bounds__(256)
void cvt_states_k(const float* __restrict__ s, bf16* __restrict__ o) {
    int idx = blockIdx.x * 256 + threadIdx.x;          // BATCH*KPAD total
    int row = idx / KPAD;
    int col = idx - row * KPAD;
    float v = (col < SDIM) ? s[row * SDIM + col] : 0.0f;
    o[idx] = __float2bfloat16(v);
}

// in fp32 [K][N] -> out bf16 [N][Kpad] (transposed), zero-pad k in [K,Kpad)
// block (32,8); grid (N/32, Kpad/32). N must be multiple of 32.
__global__ __launch_bounds__(256)
void transpose_cvt_k(const float* __restrict__ in, bf16* __restrict__ out,
                     int K, int N, int Kpad) {
    __shared__ float tile[32][33];
    int kb = blockIdx.y * 32, nb = blockIdx.x * 32;
    int tx = threadIdx.x, ty = threadIdx.y;
    #pragma unroll
    for (int i = 0; i < 32; i += 8) {
        int k = kb + ty + i, n = nb + tx;
        tile[ty + i][tx] = (k < K) ? in[(size_t)k * N + n] : 0.0f;
    }
    __syncthreads();
    #pragma unroll
    for (int i = 0; i < 32; i += 8) {
        int n = nb + ty + i, k = kb + tx;
        if (k < Kpad) out[(size_t)n * Kpad + k] = __float2bfloat16(tile[tx][ty + i]);
    }
}

// ---------------- bf16 MFMA GEMM ----------------
// C[M][N] = epilogue(A[M][K] @ BT[N][K]^T + bias)
// MODE 0: tanh -> bf16 out;  MODE 1: raw -> fp32 out
// block = 256 (4 waves). tile BM=64, BN=64, BK=32.
// grid = (N/64, M/64). M mult of 64, N mult of 64, K mult of 32.
template<int MODE>
__global__ __launch_bounds__(256)
void gemm_bt(const bf16* __restrict__ A, const bf16* __restrict__ BT,
             const float* __restrict__ bias, void* __restrict__ Cout,
             int M, int N, int K) {
    const int n0 = blockIdx.x * 64;
    const int m0 = blockIdx.y * 64;
    const int tid  = threadIdx.x;
    const int wave = tid >> 6;
    const int lane = tid & 63;

    __shared__ __align__(16) bf16 As[64][40];   // 32 + 8 pad, rowstride 80 B
    __shared__ __align__(16) bf16 Bs[64][40];

    // staging: each thread loads 8 contiguous bf16 (16 B) along k
    const int sr = tid >> 2;           // 0..63 (tile row)
    const int sc = (tid & 3) * 8;      // 0,8,16,24 (k offset)

    f32x4 acc[4];
    #pragma unroll
    for (int i = 0; i < 4; i++) acc[i] = (f32x4){0.f, 0.f, 0.f, 0.f};

    const int frow = lane & 15;        // m (A) / n (B) index within 16
    const int koff = (lane >> 4) * 8;  // k offset: 0,8,16,24

    const bf16* ag = A  + (size_t)(m0 + sr) * K + sc;
    const bf16* bg = BT + (size_t)(n0 + sr) * K + sc;

    for (int k0 = 0; k0 < K; k0 += 32) {
        uint4v av = *(const uint4v*)(ag + k0);
        uint4v bv = *(const uint4v*)(bg + k0);
        *(uint4v*)&As[sr][sc] = av;
        *(uint4v*)&Bs[sr][sc] = bv;
        __syncthreads();

        // A frag: A[m = frow][k = koff + j], contiguous in LDS
        short8 afrag = *(const short8*)&As[wave * 16 + frow][koff];
        #pragma unroll
        for (int t = 0; t < 4; t++) {
            // B frag: B[k = koff + j][n = frow] == BT[frow][koff + j]
            short8 bfrag = *(const short8*)&Bs[t * 16 + frow][koff];
            acc[t] = __builtin_amdgcn_mfma_f32_16x16x32_bf16(afrag, bfrag, acc[t], 0, 0, 0);
        }
        __syncthreads();
    }

    // epilogue: C/D layout col = lane&15, row = (lane>>4)*4 + r
    const int orow = m0 + wave * 16 + (lane >> 4) * 4;
    const int ocol = n0 + (lane & 15);
    #pragma unroll
    for (int t = 0; t < 4; t++) {
        int col = ocol + t * 16;
        float bv = bias[col];
        #pragma unroll
        for (int r = 0; r < 4; r++) {
            float val = acc[t][r] + bv;
            size_t off = (size_t)(orow + r) * N + col;
            if (MODE == 0) ((bf16*)Cout)[off] = __float2bfloat16(tanhf(val));
            else           ((float*)Cout)[off] = val;
        }
    }
}

// ---------------- masked softmax (in-place on d_out) ----------------
// one block (256 threads) per row; 16 cols per thread.
// mask MUST use original fp32 states (exact fp32 compare as in reference).
__global__ __launch_bounds__(256)
void masked_softmax_k(float* __restrict__ logits, const float* __restrict__ states,
                      const int* __restrict__ act) {
    const int row  = blockIdx.x;
    const int t    = threadIdx.x;
    const int lane = t & 63, wave = t >> 6;

    __shared__ float wl[NW];
    __shared__ float redm[4], reds[4];
    __shared__ float smax, ssum;

    if (t < NW) wl[t] = states[row * SDIM + NS + t];
    __syncthreads();
    const float wl0 = wl[0], wl1 = wl[1], wl2 = wl[2],
                wl3 = wl[3], wl4 = wl[4], wl5 = wl[5];

    float* lrow = logits + (size_t)row * NA;
    float v[16];
    float lmax = -1e30f;
    #pragma unroll
    for (int i = 0; i < 16; i++) {
        int c = i * 256 + t;
        float lg = lrow[c];
        const int* a = act + c * 6;
        bool f = ((float)a[0] <= wl0) & ((float)a[1] <= wl1) & ((float)a[2] <= wl2)
               & ((float)a[3] <= wl3) & ((float)a[4] <= wl4) & ((float)a[5] <= wl5);
        // log(1 + 1e-9) == 0.0f in fp32; log(1e-9f) = -20.7232658
        lg += f ? 0.0f : -20.7232658f;
        v[i] = lg;
        lmax = fmaxf(lmax, lg);
    }
    #pragma unroll
    for (int o = 32; o > 0; o >>= 1) lmax = fmaxf(lmax, __shfl_down(lmax, o, 64));
    if (lane == 0) redm[wave] = lmax;
    __syncthreads();
    if (t == 0) smax = fmaxf(fmaxf(redm[0], redm[1]), fmaxf(redm[2], redm[3]));
    __syncthreads();
    const float bmax = smax;

    float s = 0.f;
    #pragma unroll
    for (int i = 0; i < 16; i++) { v[i] = expf(v[i] - bmax); s += v[i]; }
    #pragma unroll
    for (int o = 32; o > 0; o >>= 1) s += __shfl_down(s, o, 64);
    if (lane == 0) reds[wave] = s;
    __syncthreads();
    if (t == 0) ssum = reds[0] + reds[1] + reds[2] + reds[3];
    __syncthreads();
    const float inv = 1.0f / ssum;

    #pragma unroll
    for (int i = 0; i < 16; i++) lrow[i * 256 + t] = v[i] * inv;
}

// ---------------- launch ----------------
extern "C" void kernel_launch(void* const* d_in, const int* in_sizes, int n_in,
                              void* d_out, int out_size, void* d_ws, size_t ws_size,
                              hipStream_t stream) {
    const float* states = (const float*)d_in[0];
    const float* W1 = (const float*)d_in[1];
    const float* b1 = (const float*)d_in[2];
    const float* W2 = (const float*)d_in[3];
    const float* b2 = (const float*)d_in[4];
    const float* Wh = (const float*)d_in[5];
    const float* bh = (const float*)d_in[6];
    const int*   act = (const int*)d_in[7];
    float* out = (float*)d_out;

    char* ws = (char*)d_ws;
    bf16* statesb = (bf16*)ws; ws += (size_t)BATCH * KPAD * 2;
    bf16* w1bt    = (bf16*)ws; ws += (size_t)HID * KPAD * 2;
    bf16* w2bt    = (bf16*)ws; ws += (size_t)HID * HID * 2;
    bf16* whbt    = (bf16*)ws; ws += (size_t)NA * HID * 2;
    bf16* h1      = (bf16*)ws; ws += (size_t)BATCH * HID * 2;
    bf16* h2      = (bf16*)ws; ws += (size_t)BATCH * HID * 2;

    dim3 tb(32, 8);
    cvt_states_k<<<(BATCH * KPAD) / 256, 256, 0, stream>>>(states, statesb);
    transpose_cvt_k<<<dim3(HID / 32, KPAD / 32), tb, 0, stream>>>(W1, w1bt, SDIM, HID, KPAD);
    transpose_cvt_k<<<dim3(HID / 32, HID / 32), tb, 0, stream>>>(W2, w2bt, HID, HID, HID);
    transpose_cvt_k<<<dim3(NA / 32, HID / 32), tb, 0, stream>>>(Wh, whbt, HID, NA, HID);

    gemm_bt<0><<<dim3(HID / 64, BATCH / 64), 256, 0, stream>>>(statesb, w1bt, b1, h1, BATCH, HID, KPAD);
    gemm_bt<0><<<dim3(HID / 64, BATCH / 64), 256, 0, stream>>>(h1, w2bt, b2, h2, BATCH, HID, HID);
    gemm_bt<1><<<dim3(NA / 64, BATCH / 64), 256, 0, stream>>>(h2, whbt, bh, out, BATCH, NA, HID);

    masked_softmax_k<<<BATCH, 256, 0, stream>>>(out, states, act);
}

// Round 2
// 342.199 us; speedup vs baseline: 1.2274x; 1.2274x over previous
//
#include <hip/hip_runtime.h>
#include <hip/hip_bf16.h>
#include <math.h>

using bf16 = __hip_bfloat16;
typedef __attribute__((ext_vector_type(8))) short short8;
typedef __attribute__((ext_vector_type(4))) float f32x4;
typedef __attribute__((ext_vector_type(4))) unsigned int u32x4;

#define BATCH 8192
#define SDIM  70
#define NS    64
#define NW    6
#define HID   1024
#define NA    4096
#define KPAD  96   // states K padded 70 -> 96 (multiple of 32)

// async global->LDS, 16 B per lane. LDS dest is wave-uniform base + lane*16.
__device__ __forceinline__ void gld_lds16(const bf16* g, bf16* l) {
    __builtin_amdgcn_global_load_lds(
        (const __attribute__((address_space(1))) void*)g,
        (__attribute__((address_space(3))) void*)l, 16, 0, 0);
}

// ---------------- conversion kernels ----------------

__global__ __launch_bounds__(256)
void cvt_states_k(const float* __restrict__ s, bf16* __restrict__ o) {
    int idx = blockIdx.x * 256 + threadIdx.x;          // BATCH*KPAD total
    int row = idx / KPAD;
    int col = idx - row * KPAD;
    float v = (col < SDIM) ? s[row * SDIM + col] : 0.0f;
    o[idx] = __float2bfloat16(v);
}

// fp32 [K][N] -> bf16 [N][Kpad] transposed, zero-pad k in [K,Kpad)
__global__ __launch_bounds__(256)
void transpose_cvt_k(const float* __restrict__ in, bf16* __restrict__ out,
                     int K, int N, int Kpad) {
    __shared__ float tile[32][33];
    int kb = blockIdx.y * 32, nb = blockIdx.x * 32;
    int tx = threadIdx.x, ty = threadIdx.y;
    #pragma unroll
    for (int i = 0; i < 32; i += 8) {
        int k = kb + ty + i, n = nb + tx;
        tile[ty + i][tx] = (k < K) ? in[(size_t)k * N + n] : 0.0f;
    }
    __syncthreads();
    #pragma unroll
    for (int i = 0; i < 32; i += 8) {
        int n = nb + ty + i, k = kb + tx;
        if (k < Kpad) out[(size_t)n * Kpad + k] = __float2bfloat16(tile[tx][ty + i]);
    }
}

// pack action columns: 6 fields x 5 bits
__global__ __launch_bounds__(256)
void pack_act_k(const int* __restrict__ act, unsigned* __restrict__ pact) {
    int c = blockIdx.x * 256 + threadIdx.x;
    if (c < NA) {
        const int* a = act + c * 6;
        unsigned p = 0;
        #pragma unroll
        for (int i = 0; i < 6; i++) p |= ((unsigned)a[i]) << (5 * i);
        pact[c] = p;
    }
}

// ---------------- bf16 MFMA GEMM, m97 structure ----------------
// C[M][N] = epilogue(A[M][K] @ BT[N][K]^T + bias)
// MODE 0: tanh -> bf16; MODE 1: raw -> fp32
// 256 threads = 4 waves; tile 128x128, BK=32; each wave computes 64x64.
template<int MODE>
__global__ __launch_bounds__(256)
void gemm128(const bf16* __restrict__ A, const bf16* __restrict__ BT,
             const float* __restrict__ bias, void* __restrict__ Cout,
             int M, int N, int K) {
    const int n0 = blockIdx.x * 128;
    const int m0 = blockIdx.y * 128;
    const int tid  = threadIdx.x;
    const int wave = tid >> 6;
    const int lane = tid & 63;

    __shared__ __align__(16) bf16 As[128 * 32];  // row-major, rowstride 32 (64 B), no pad
    __shared__ __align__(16) bf16 Bs[128 * 32];

    // staging: wave w covers rows [32w, 32w+32); lane i -> row 32w+(i>>2), k (i&3)*8
    const int srow = wave * 32 + (lane >> 2);
    const int sk   = (lane & 3) * 8;
    const bf16* ag = A  + (size_t)(m0 + srow) * K + sk;
    const bf16* bg = BT + (size_t)(n0 + srow) * K + sk;
    bf16* asl = &As[(wave * 32) * 32];          // wave-uniform LDS base
    bf16* bsl = &Bs[(wave * 32) * 32];

    f32x4 acc[4][4];
    #pragma unroll
    for (int i = 0; i < 4; i++)
        #pragma unroll
        for (int j = 0; j < 4; j++) acc[i][j] = (f32x4){0.f, 0.f, 0.f, 0.f};

    const int rb = (wave >> 1) * 64;   // wave's m block within tile
    const int cb = (wave & 1) * 64;    // wave's n block within tile
    const int fr = lane & 15;
    const int koff = (lane >> 4) * 8;

    for (int k0 = 0; k0 < K; k0 += 32) {
        gld_lds16(ag + k0,          asl);
        gld_lds16(ag + k0 + 16 * K, asl + 16 * 32);
        gld_lds16(bg + k0,          bsl);
        gld_lds16(bg + k0 + 16 * K, bsl + 16 * 32);
        __syncthreads();

        short8 af[4], bf[4];
        #pragma unroll
        for (int i = 0; i < 4; i++)
            af[i] = *(const short8*)&As[(rb + i * 16 + fr) * 32 + koff];
        #pragma unroll
        for (int j = 0; j < 4; j++)
            bf[j] = *(const short8*)&Bs[(cb + j * 16 + fr) * 32 + koff];
        #pragma unroll
        for (int i = 0; i < 4; i++)
            #pragma unroll
            for (int j = 0; j < 4; j++)
                acc[i][j] = __builtin_amdgcn_mfma_f32_16x16x32_bf16(af[i], bf[j], acc[i][j], 0, 0, 0);
        __syncthreads();
    }

    // C/D layout: col = lane&15, row = (lane>>4)*4 + r
    const int orow = m0 + rb + (lane >> 4) * 4;
    const int ocol = n0 + cb + fr;
    #pragma unroll
    for (int j = 0; j < 4; j++) {
        int col = ocol + j * 16;
        float bv = bias[col];
        #pragma unroll
        for (int i = 0; i < 4; i++) {
            int rbase = orow + i * 16;
            #pragma unroll
            for (int r = 0; r < 4; r++) {
                float val = acc[i][j][r] + bv;
                size_t off = (size_t)(rbase + r) * N + col;
                if (MODE == 0) ((bf16*)Cout)[off] = __float2bfloat16(tanhf(val));
                else           ((float*)Cout)[off] = val;
            }
        }
    }
}

// ---------------- masked softmax (in-place on d_out) ----------------
// one block per row; float4-vectorized; SWAR feasibility test.
__global__ __launch_bounds__(256)
void masked_softmax_k(float* __restrict__ logits, const float* __restrict__ states,
                      const unsigned* __restrict__ pact) {
    const int row  = blockIdx.x;
    const int t    = threadIdx.x;
    const int lane = t & 63, wave = t >> 6;

    __shared__ float redm[4], reds[4];
    __shared__ float smax, ssum;

    // packed thresholds: a_i <= wl_i  <=>  a_i <= floor(wl_i)  (a_i integer)
    const float* wl = states + (size_t)row * SDIM + NS;
    unsigned T = 0;
    #pragma unroll
    for (int i = 0; i < 6; i++) T |= ((unsigned)(int)wl[i]) << (5 * i);
    const unsigned H  = 0x21084210u;   // guard bit (bit4) of each 5-bit field
    const unsigned TH = T | H;

    float* lrow = logits + (size_t)row * NA;
    f32x4 v[4];
    float lmax = -1e30f;
    #pragma unroll
    for (int i = 0; i < 4; i++) {
        int c = i * 1024 + t * 4;
        v[i] = *(const f32x4*)(lrow + c);
        u32x4 p = *(const u32x4*)(pact + c);
        #pragma unroll
        for (int e = 0; e < 4; e++) {
            bool f = (((TH - p[e]) & H) == H);   // all fields t_i >= a_i
            float lg = v[i][e] + (f ? 0.0f : -20.7232658f);
            v[i][e] = lg;
            lmax = fmaxf(lmax, lg);
        }
    }
    #pragma unroll
    for (int o = 32; o > 0; o >>= 1) lmax = fmaxf(lmax, __shfl_down(lmax, o, 64));
    if (lane == 0) redm[wave] = lmax;
    __syncthreads();
    if (t == 0) smax = fmaxf(fmaxf(redm[0], redm[1]), fmaxf(redm[2], redm[3]));
    __syncthreads();
    const float bmax = smax;

    float s = 0.f;
    #pragma unroll
    for (int i = 0; i < 4; i++)
        #pragma unroll
        for (int e = 0; e < 4; e++) { float ev = __expf(v[i][e] - bmax); v[i][e] = ev; s += ev; }
    #pragma unroll
    for (int o = 32; o > 0; o >>= 1) s += __shfl_down(s, o, 64);
    if (lane == 0) reds[wave] = s;
    __syncthreads();
    if (t == 0) ssum = reds[0] + reds[1] + reds[2] + reds[3];
    __syncthreads();
    const float inv = 1.0f / ssum;

    #pragma unroll
    for (int i = 0; i < 4; i++) {
        int c = i * 1024 + t * 4;
        f32x4 o4 = { v[i][0] * inv, v[i][1] * inv, v[i][2] * inv, v[i][3] * inv };
        *(f32x4*)(lrow + c) = o4;
    }
}

// ---------------- launch ----------------
extern "C" void kernel_launch(void* const* d_in, const int* in_sizes, int n_in,
                              void* d_out, int out_size, void* d_ws, size_t ws_size,
                              hipStream_t stream) {
    const float* states = (const float*)d_in[0];
    const float* W1 = (const float*)d_in[1];
    const float* b1 = (const float*)d_in[2];
    const float* W2 = (const float*)d_in[3];
    const float* b2 = (const float*)d_in[4];
    const float* Wh = (const float*)d_in[5];
    const float* bh = (const float*)d_in[6];
    const int*   act = (const int*)d_in[7];
    float* out = (float*)d_out;

    char* ws = (char*)d_ws;
    bf16* statesb = (bf16*)ws; ws += (size_t)BATCH * KPAD * 2;
    bf16* w1bt    = (bf16*)ws; ws += (size_t)HID * KPAD * 2;
    bf16* w2bt    = (bf16*)ws; ws += (size_t)HID * HID * 2;
    bf16* whbt    = (bf16*)ws; ws += (size_t)NA * HID * 2;
    bf16* h1      = (bf16*)ws; ws += (size_t)BATCH * HID * 2;
    bf16* h2      = (bf16*)ws; ws += (size_t)BATCH * HID * 2;
    unsigned* pact = (unsigned*)ws; ws += (size_t)NA * 4;

    dim3 tb(32, 8);
    cvt_states_k<<<(BATCH * KPAD) / 256, 256, 0, stream>>>(states, statesb);
    transpose_cvt_k<<<dim3(HID / 32, KPAD / 32), tb, 0, stream>>>(W1, w1bt, SDIM, HID, KPAD);
    transpose_cvt_k<<<dim3(HID / 32, HID / 32), tb, 0, stream>>>(W2, w2bt, HID, HID, HID);
    transpose_cvt_k<<<dim3(NA / 32, HID / 32), tb, 0, stream>>>(Wh, whbt, HID, NA, HID);
    pack_act_k<<<NA / 256, 256, 0, stream>>>(act, pact);

    gemm128<0><<<dim3(HID / 128, BATCH / 128), 256, 0, stream>>>(statesb, w1bt, b1, h1, BATCH, HID, KPAD);
    gemm128<0><<<dim3(HID / 128, BATCH / 128), 256, 0, stream>>>(h1, w2bt, b2, h2, BATCH, HID, HID);
    gemm128<1><<<dim3(NA / 128, BATCH / 128), 256, 0, stream>>>(h2, whbt, bh, out, BATCH, NA, HID);

    masked_softmax_k<<<BATCH, 256, 0, stream>>>(out, states, pact);
}